// Round 15
// baseline (111.552 us; speedup 1.0000x reference)
//
#include <hip/hip_runtime.h>
#include <hip/hip_bf16.h>

#define EPS_BN 1e-5f
#define MFMA16 __builtin_amdgcn_mfma_f32_16x16x32_bf16

typedef unsigned char uchar;
typedef short short8 __attribute__((ext_vector_type(8)));
typedef float f32x4 __attribute__((ext_vector_type(4)));

__device__ __forceinline__ ushort f2bf(float f) {
    __hip_bfloat16 h = __float2bfloat16(f);     // RNE; compiler packs pairs
    return *(ushort*)&h;
}
__device__ __forceinline__ float bf2f(ushort h) {
    return __uint_as_float(((unsigned)h) << 16);
}
__device__ __forceinline__ void gload_lds16(const void* g, void* l) {
    __builtin_amdgcn_global_load_lds(
        (const __attribute__((address_space(1))) void*)g,
        (__attribute__((address_space(3))) void*)l, 16, 0, 0);
}

// ---------------------------------------------------------------------------
// R15: fat waves (32 MFMA/K-step, R13's per-wave shape) x 2 blocks/CU (TLP
// to overlap staging drains, m114). Block = 128px x 128co, 256 thr / 4
// waves (wave 64px x 64co, acc[4][4]). A-halo 33KB + B dbuf 32KB = 65KB
// < 80KB -> 2 blocks/CU; grid 512 = exactly 2/CU, XCD-swizzled.
// Sync skeleton unchanged from R13 (issue-early dbuf, 2 barriers/step,
// halo restage per kh).
// MFMA maps (mfma_f32_16x16x32_bf16):
//   A: lane(lr,lg)=lr+16*lg holds A[row=lr][k=lg*8..+8)
//   B: lane holds B[k=lg*8..+8)[col=lr]; weights [co][ci] so co=col
//   D: lane holds D[row=lg*4+r][col=lr], r=0..3
// ---------------------------------------------------------------------------

__global__ __launch_bounds__(256) void mask_kernel(const int* __restrict__ mask,
                                                   uchar* __restrict__ m1,
                                                   int* __restrict__ cnt)
{
    int idx = blockIdx.x * 256 + threadIdx.x;   // 65536
    int ow = idx & 127;
    int oh = (idx >> 7) & 127;
    int b  = idx >> 14;
    bool act = false;
    #pragma unroll
    for (int kh = 0; kh < 3; ++kh) {
        int ih = 2*oh - 1 + kh;
        if ((unsigned)ih >= 256u) continue;
        #pragma unroll
        for (int kw = 0; kw < 3; ++kw) {
            int iw = 2*ow - 1 + kw;
            if ((unsigned)iw >= 256u) continue;
            if (mask[(b*256 + ih)*256 + iw] == 0) act = true;
        }
    }
    m1[idx] = act ? 1 : 0;
    unsigned long long bal = __ballot(act);
    if ((threadIdx.x & 63) == 0)
        atomicAdd(cnt, (int)__popcll(bal));
}

__global__ __launch_bounds__(256) void wcvt_kernel(const float* __restrict__ w1,
                                                   const float* __restrict__ w2,
                                                   ushort* __restrict__ w1T,
                                                   ushort* __restrict__ w2T)
{
    int idx = blockIdx.x * 256 + threadIdx.x;   // 221184 total
    if (idx < 73728) {                          // 9*128*64
        int ci = idx & 63;
        int co = (idx >> 6) & 127;
        int s  = idx >> 13;
        w1T[idx] = f2bf(w1[(s*64 + ci)*128 + co]);
    } else if (idx < 221184) {
        int i  = idx - 73728;                   // 9*128*128
        int ci = i & 127;
        int co = (i >> 7) & 127;
        int s  = i >> 14;
        w2T[i] = f2bf(w2[(s*128 + ci)*128 + co]);
    }
}

// conv1: 3x3 s2, 64->128. Block = one output row (b,oh) = 128px x 128co.
// A-halo per kh: Ah[258][64] bf16 (33,024B), swizzle ^(((c>>1)&7)<<4).
// B per tap 16KB dbuf. 9 steps + 2 restages.
__global__ __launch_bounds__(256) void conv1_mfma(const float* __restrict__ x,
                                                  const int* __restrict__ mask,
                                                  const ushort* __restrict__ w1T,
                                                  const uchar* __restrict__ m1,
                                                  ushort* __restrict__ out1,
                                                  float* __restrict__ stats)
{
    __shared__ ushort Ah[258 * 64];    // 33,024 B
    __shared__ ushort Bd[2][8192];     // 2 x 16 KB

    const int t     = threadIdx.x;
    const int lane  = t & 63;
    const int wv    = t >> 6;          // 0..3
    const int wbase = t & ~63;
    const int bid   = blockIdx.x;
    const int L     = (bid & 7) * 64 + (bid >> 3);   // XCD-chunked, 512%8==0
    const int oh    = L & 127;
    const int b     = L >> 7;

    const int wm = wv >> 1, wn = wv & 1;    // wave: 64px x 64co
    const int lr = lane & 15, lg = lane >> 4;

    auto stageA = [&](int kh) {
        int ih = 2*oh + kh - 1;
        bool rok = ((unsigned)ih < 256u);
        int ihc = ih < 0 ? 0 : (ih > 255 ? 255 : ih);
        const float* xr = x + (size_t)(b*256 + ihc) * 256 * 64;
        const int*   mr = mask + (size_t)(b*256 + ihc) * 256;
        for (int idx = t; idx < 2064; idx += 256) {   // 258 cols x 8 chunks
            int c = idx >> 3, k = idx & 7;
            int iw = c - 1;
            short8 v = {0,0,0,0,0,0,0,0};
            if (rok && (unsigned)iw < 256u && mr[iw] == 0) {
                const float* p = xr + (size_t)iw*64 + k*8;
                float4 fa = *(const float4*)p;
                float4 fb = *(const float4*)(p + 4);
                v[0]=(short)f2bf(fa.x); v[1]=(short)f2bf(fa.y);
                v[2]=(short)f2bf(fa.z); v[3]=(short)f2bf(fa.w);
                v[4]=(short)f2bf(fb.x); v[5]=(short)f2bf(fb.y);
                v[6]=(short)f2bf(fb.z); v[7]=(short)f2bf(fb.w);
            }
            int ad = (c*128 + k*16) ^ ((((unsigned)c >> 1) & 7) << 4);
            *(short8*)((char*)Ah + ad) = v;
        }
    };
    const int coB = t >> 3;            // co = r*32 + coB
    const int kB  = t & 7;
    auto dmaB = [&](int buf, int tap) {
        #pragma unroll
        for (int r = 0; r < 4; ++r) {
            int co = r*32 + coB;
            const ushort* gp = w1T + (size_t)tap*8192 + (size_t)co*64
                             + ((kB ^ (co & 7)) << 3);
            gload_lds16(gp, &Bd[buf][(size_t)(r*256 + wbase)*8]);
        }
    };

    f32x4 acc[4][4];
    #pragma unroll
    for (int mi = 0; mi < 4; ++mi)
        #pragma unroll
        for (int ni = 0; ni < 4; ++ni)
            acc[mi][ni] = (f32x4){0.f, 0.f, 0.f, 0.f};

    stageA(0);
    dmaB(0, 0);
    __syncthreads();

    #pragma unroll
    for (int kt = 0; kt < 9; ++kt) {
        const int kw = kt % 3, cb = kt & 1;
        if (kt < 8) dmaB(cb ^ 1, kt + 1);          // issue BEFORE compute
        const char* Ab = (const char*)Ah;
        const char* Bb = (const char*)Bd[cb];
        __builtin_amdgcn_s_setprio(1);
        #pragma unroll
        for (int ks = 0; ks < 2; ++ks) {
            short8 af[4], bfr[4];
            #pragma unroll
            for (int mi = 0; mi < 4; ++mi) {
                int px = wm*64 + mi*16 + lr;
                int c  = 2*px + kw;                // halo col (iw = c-1)
                af[mi] = *(const short8*)(Ab +
                    ((c*128 + ks*64 + lg*16) ^ ((((unsigned)c >> 1) & 7) << 4)));
            }
            #pragma unroll
            for (int ni = 0; ni < 4; ++ni) {
                int co = wn*64 + ni*16 + lr;
                bfr[ni] = *(const short8*)(Bb +
                    ((co*128 + ks*64 + lg*16) ^ ((co & 7) << 4)));
            }
            #pragma unroll
            for (int mi = 0; mi < 4; ++mi)
                #pragma unroll
                for (int ni = 0; ni < 4; ++ni)
                    acc[mi][ni] = MFMA16(af[mi], bfr[ni], acc[mi][ni], 0, 0, 0);
        }
        __builtin_amdgcn_s_setprio(0);
        __syncthreads();
        if (kw == 2 && kt < 8) {                    // kh boundary: restage halo
            stageA(kt/3 + 1);
            __syncthreads();
        }
    }

    const size_t pixbase = (size_t)(b*128 + oh) * 128;
    #pragma unroll
    for (int mi = 0; mi < 4; ++mi) {
        #pragma unroll
        for (int ni = 0; ni < 4; ++ni) {
            int p  = wm*64 + mi*16 + lg*4;
            int co = wn*64 + ni*16 + lr;
            #pragma unroll
            for (int r = 0; r < 4; ++r)
                out1[(pixbase + p + r)*128 + co] = f2bf(acc[mi][ni][r]);
        }
    }

    // ---- fused BN1 stats ----
    float s4[4] = {0.f,0.f,0.f,0.f}, q4[4] = {0.f,0.f,0.f,0.f};
    #pragma unroll
    for (int mi = 0; mi < 4; ++mi) {
        const uchar* mp = m1 + pixbase + wm*64 + mi*16 + lg*4;
        #pragma unroll
        for (int r = 0; r < 4; ++r) {
            float a = mp[r] ? 1.f : 0.f;
            #pragma unroll
            for (int ni = 0; ni < 4; ++ni) {
                float av = a * acc[mi][ni][r];
                s4[ni] += av;
                q4[ni] += av * acc[mi][ni][r];
            }
        }
    }
    float* red = (float*)Ah;           // halo buffer free after main loop
    const int rrow = wm*4 + lg;        // 0..7
    #pragma unroll
    for (int ni = 0; ni < 4; ++ni) {
        red[rrow*128 + wn*64 + ni*16 + lr]        = s4[ni];
        red[1024 + rrow*128 + wn*64 + ni*16 + lr] = q4[ni];
    }
    __syncthreads();
    if (t < 128) {
        float v = 0.f, q = 0.f;
        #pragma unroll
        for (int rr = 0; rr < 8; ++rr) { v += red[rr*128 + t]; q += red[1024 + rr*128 + t]; }
        atomicAdd(&stats[t], v);
        atomicAdd(&stats[128 + t], q);
    }
}

// conv2: 3x3 s1, 128->128 on RAW out1 (BN1+ReLU+m1 fused into halo staging).
// Block = one output row x 128co. Ah[130][128] bf16 (33,280B), swizzle
// ^((c&7)<<4). B per (tap,ci-half) 16KB dbuf; 18 steps + 2 restages.
__global__ __launch_bounds__(256) void conv2_mfma(const ushort* __restrict__ a,
                                                  const ushort* __restrict__ w2T,
                                                  const uchar* __restrict__ m1,
                                                  const float* __restrict__ sb,
                                                  float* __restrict__ outraw,
                                                  float* __restrict__ stats)
{
    __shared__ ushort Ah[130 * 128];   // 33,280 B
    __shared__ ushort Bd[2][8192];     // 2 x 16 KB
    __shared__ float scb[256];

    const int t     = threadIdx.x;
    const int lane  = t & 63;
    const int wv    = t >> 6;
    const int wbase = t & ~63;
    const int bid   = blockIdx.x;
    const int L     = (bid & 7) * 64 + (bid >> 3);
    const int oh    = L & 127;
    const int b     = L >> 7;

    const int wm = wv >> 1, wn = wv & 1;
    const int lr = lane & 15, lg = lane >> 4;

    scb[t & 255] = sb[t & 255];

    auto stageA = [&](int kh) {
        int ih = oh + kh - 1;
        bool rok = ((unsigned)ih < 128u);
        int ihc = ih < 0 ? 0 : (ih > 127 ? 127 : ih);
        const ushort* ar = a + (size_t)(b*128 + ihc) * 128 * 128;
        const uchar*  mr = m1 + (size_t)(b*128 + ihc) * 128;
        for (int idx = t; idx < 2080; idx += 256) {   // 130 cols x 16 chunks
            int c = idx >> 4, k = idx & 15;
            int iw = c - 1;
            short8 v = {0,0,0,0,0,0,0,0};
            if (rok && (unsigned)iw < 128u && mr[iw]) {
                short8 rv = *(const short8*)(ar + (size_t)iw*128 + k*8);
                #pragma unroll
                for (int j = 0; j < 8; ++j) {
                    float f = fmaf(bf2f((ushort)rv[j]), scb[k*8 + j], scb[128 + k*8 + j]);
                    v[j] = (short)f2bf(fmaxf(f, 0.f));
                }
            }
            int ad = (c*256 + k*16) ^ ((c & 7) << 4);
            *(short8*)((char*)Ah + ad) = v;
        }
    };
    const int coB = t >> 3;
    const int kB  = t & 7;
    auto dmaB = [&](int buf, int kt) {
        const int s = kt / 6, j = kt % 6;
        const int tap = s*3 + (j >> 1);
        const int h = j & 1;
        #pragma unroll
        for (int r = 0; r < 4; ++r) {
            int co = r*32 + coB;
            const ushort* gp = w2T + (size_t)tap*16384 + (size_t)co*128 + h*64
                             + ((kB ^ (co & 7)) << 3);
            gload_lds16(gp, &Bd[buf][(size_t)(r*256 + wbase)*8]);
        }
    };

    f32x4 acc[4][4];
    #pragma unroll
    for (int mi = 0; mi < 4; ++mi)
        #pragma unroll
        for (int ni = 0; ni < 4; ++ni)
            acc[mi][ni] = (f32x4){0.f, 0.f, 0.f, 0.f};

    __syncthreads();                   // scb visible
    stageA(0);
    dmaB(0, 0);
    __syncthreads();

    #pragma unroll
    for (int kt = 0; kt < 18; ++kt) {
        const int j = kt % 6;
        const int kw = j >> 1, h = j & 1, cb = kt & 1;
        if (kt < 17) dmaB(cb ^ 1, kt + 1);         // issue BEFORE compute
        const char* Ab = (const char*)Ah;
        const char* Bb = (const char*)Bd[cb];
        __builtin_amdgcn_s_setprio(1);
        #pragma unroll
        for (int ks = 0; ks < 2; ++ks) {
            short8 af[4], bfr[4];
            #pragma unroll
            for (int mi = 0; mi < 4; ++mi) {
                int px = wm*64 + mi*16 + lr;
                int c  = px + kw;                  // halo col (iw = c-1)
                af[mi] = *(const short8*)(Ab +
                    ((c*256 + h*128 + ks*64 + lg*16) ^ ((c & 7) << 4)));
            }
            #pragma unroll
            for (int ni = 0; ni < 4; ++ni) {
                int co = wn*64 + ni*16 + lr;
                bfr[ni] = *(const short8*)(Bb +
                    ((co*128 + ks*64 + lg*16) ^ ((co & 7) << 4)));
            }
            #pragma unroll
            for (int mi = 0; mi < 4; ++mi)
                #pragma unroll
                for (int ni = 0; ni < 4; ++ni)
                    acc[mi][ni] = MFMA16(af[mi], bfr[ni], acc[mi][ni], 0, 0, 0);
        }
        __builtin_amdgcn_s_setprio(0);
        __syncthreads();
        if (j == 5 && kt < 17) {                    // kh boundary: restage halo
            stageA(kt/6 + 1);
            __syncthreads();
        }
    }

    const size_t pixbase = (size_t)(b*128 + oh) * 128;
    #pragma unroll
    for (int mi = 0; mi < 4; ++mi) {
        #pragma unroll
        for (int ni = 0; ni < 4; ++ni) {
            int p  = wm*64 + mi*16 + lg*4;
            int co = wn*64 + ni*16 + lr;
            #pragma unroll
            for (int r = 0; r < 4; ++r)
                outraw[(pixbase + p + r)*128 + co] = acc[mi][ni][r];
        }
    }

    // ---- fused BN2 stats ----
    float s4[4] = {0.f,0.f,0.f,0.f}, q4[4] = {0.f,0.f,0.f,0.f};
    #pragma unroll
    for (int mi = 0; mi < 4; ++mi) {
        const uchar* mp = m1 + pixbase + wm*64 + mi*16 + lg*4;
        #pragma unroll
        for (int r = 0; r < 4; ++r) {
            float a0 = mp[r] ? 1.f : 0.f;
            #pragma unroll
            for (int ni = 0; ni < 4; ++ni) {
                float av = a0 * acc[mi][ni][r];
                s4[ni] += av;
                q4[ni] += av * acc[mi][ni][r];
            }
        }
    }
    float* red = (float*)Ah;
    const int rrow = wm*4 + lg;
    #pragma unroll
    for (int ni = 0; ni < 4; ++ni) {
        red[rrow*128 + wn*64 + ni*16 + lr]        = s4[ni];
        red[1024 + rrow*128 + wn*64 + ni*16 + lr] = q4[ni];
    }
    __syncthreads();
    if (t < 128) {
        float v = 0.f, q = 0.f;
        #pragma unroll
        for (int rr = 0; rr < 8; ++rr) { v += red[rr*128 + t]; q += red[1024 + rr*128 + t]; }
        atomicAdd(&stats[t], v);
        atomicAdd(&stats[128 + t], q);
    }
}

__global__ void finalize_kernel(const float* __restrict__ stats,
                                const float* __restrict__ gamma,
                                const float* __restrict__ beta,
                                float* __restrict__ sbout,
                                const int* __restrict__ cnt)
{
    int c = threadIdx.x;   // 128
    float n = (float)(*cnt);
    float mean = stats[c] / n;
    float var  = stats[128 + c] / n - mean*mean;
    var = fmaxf(var, 0.f);
    float scale = gamma[c] * rsqrtf(var + EPS_BN);
    sbout[c]       = scale;
    sbout[128 + c] = beta[c] - mean*scale;
}

// d_out <- m1 ? raw*sc2+bi2 : 0 (f32 in-place)
__global__ __launch_bounds__(256) void apply_kernel(float* __restrict__ out,
                                                    const uchar* __restrict__ m1,
                                                    const float* __restrict__ sb)
{
    int idx4 = blockIdx.x * 256 + threadIdx.x;   // 2,097,152 float4s
    int pos = idx4 >> 5;
    int c4  = (idx4 & 31) << 2;
    float4 v = ((const float4*)out)[idx4];
    float4 r = make_float4(0.f, 0.f, 0.f, 0.f);
    if (m1[pos]) {
        r.x = fmaf(v.x, sb[c4+0], sb[128+c4+0]);
        r.y = fmaf(v.y, sb[c4+1], sb[128+c4+1]);
        r.z = fmaf(v.z, sb[c4+2], sb[128+c4+2]);
        r.w = fmaf(v.w, sb[c4+3], sb[128+c4+3]);
    }
    ((float4*)out)[idx4] = r;
}

extern "C" void kernel_launch(void* const* d_in, const int* in_sizes, int n_in,
                              void* d_out, int out_size, void* d_ws, size_t ws_size,
                              hipStream_t stream)
{
    const float* x      = (const float*)d_in[0];
    const int*   mask   = (const int*)d_in[1];
    const float* w1     = (const float*)d_in[2];
    const float* gamma1 = (const float*)d_in[3];
    const float* beta1  = (const float*)d_in[4];
    const float* w2     = (const float*)d_in[5];
    const float* gamma2 = (const float*)d_in[6];
    const float* beta2  = (const float*)d_in[7];

    ushort* out1 = (ushort*)d_ws;                    // 65536*128 bf16 (raw conv1)
    ushort* w1T  = out1 + 8388608;                   // 9*128*64
    ushort* w2T  = w1T + 73728;                      // 9*128*128
    float* stats = (float*)(w2T + 147456);           // 512 (256 per BN)
    float* sb    = stats + 512;                      // 512 (256 per BN)
    int*   cnt   = (int*)(sb + 512);                 // 4
    uchar* m1    = (uchar*)(cnt + 4);                // 65536

    float* out = (float*)d_out;

    hipMemsetAsync(stats, 0, 1024*sizeof(float) + 4*sizeof(int), stream);

    mask_kernel <<<256, 256, 0, stream>>>(mask, m1, cnt);
    wcvt_kernel <<<864, 256, 0, stream>>>(w1, w2, w1T, w2T);
    conv1_mfma  <<<512, 256, 0, stream>>>(x, mask, w1T, m1, out1, stats);
    finalize_kernel<<<1, 128, 0, stream>>>(stats, gamma1, beta1, sb, cnt);
    conv2_mfma  <<<512, 256, 0, stream>>>(out1, w2T, m1, sb, out, stats + 256);
    finalize_kernel<<<1, 128, 0, stream>>>(stats + 256, gamma2, beta2, sb + 256, cnt);
    apply_kernel<<<8192, 256, 0, stream>>>(out, m1, sb + 256);
}

// Round 16
// 105.686 us; speedup vs baseline: 1.0555x; 1.0555x over previous
//
#include <hip/hip_runtime.h>
#include <hip/hip_bf16.h>

#define EPS_BN 1e-5f
#define MFMA16 __builtin_amdgcn_mfma_f32_16x16x32_bf16
#define VW2 do { asm volatile("s_waitcnt vmcnt(2)" ::: "memory"); __builtin_amdgcn_sched_barrier(0); } while(0)
#define VW4 do { asm volatile("s_waitcnt vmcnt(4)" ::: "memory"); __builtin_amdgcn_sched_barrier(0); } while(0)
#define LK0 do { asm volatile("s_waitcnt lgkmcnt(0)" ::: "memory"); __builtin_amdgcn_sched_barrier(0); } while(0)
#define SBAR __builtin_amdgcn_s_barrier()

typedef unsigned char uchar;
typedef short short8 __attribute__((ext_vector_type(8)));
typedef float f32x4 __attribute__((ext_vector_type(4)));

__device__ __forceinline__ ushort f2bf(float f) {
    __hip_bfloat16 h = __float2bfloat16(f);
    return *(ushort*)&h;
}
__device__ __forceinline__ float bf2f(ushort h) {
    return __uint_as_float(((unsigned)h) << 16);
}
__device__ __forceinline__ void gload_lds16(const void* g, void* l) {
    __builtin_amdgcn_global_load_lds(
        (const __attribute__((address_space(1))) void*)g,
        (__attribute__((address_space(3))) void*)l, 16, 0, 0);
}

// ---------------------------------------------------------------------------
// R16 = R13 fat geometry (256px x 128co, 512thr/8 waves, BK=64, 1 blk/CU)
//     + R12 counted-vmcnt sync (B triple-buffer, raw s_barrier; loads span
//       barriers, vmcnt never drains to 0 in steady state).
// Steady step q: compute(buf q%3) -> vmcnt(2) [B(q+1) landed, B(q+2) in
// flight] -> s_barrier -> issue B(q+3) into buf q%3. kh-boundary restages
// are full drains (2 per kernel).
// MFMA maps (mfma_f32_16x16x32_bf16):
//   A: lane(lr,lg)=lr+16*lg holds A[row=lr][k=lg*8..+8)
//   B: lane holds B[k=lg*8..+8)[col=lr]; weights [co][ci] so co=col
//   D: lane holds D[row=lg*4+r][col=lr], r=0..3
// ---------------------------------------------------------------------------

__global__ __launch_bounds__(256) void mask_kernel(const int* __restrict__ mask,
                                                   uchar* __restrict__ m1,
                                                   int* __restrict__ cnt)
{
    int idx = blockIdx.x * 256 + threadIdx.x;   // 65536
    int ow = idx & 127;
    int oh = (idx >> 7) & 127;
    int b  = idx >> 14;
    bool act = false;
    #pragma unroll
    for (int kh = 0; kh < 3; ++kh) {
        int ih = 2*oh - 1 + kh;
        if ((unsigned)ih >= 256u) continue;
        #pragma unroll
        for (int kw = 0; kw < 3; ++kw) {
            int iw = 2*ow - 1 + kw;
            if ((unsigned)iw >= 256u) continue;
            if (mask[(b*256 + ih)*256 + iw] == 0) act = true;
        }
    }
    m1[idx] = act ? 1 : 0;
    unsigned long long bal = __ballot(act);
    if ((threadIdx.x & 63) == 0)
        atomicAdd(cnt, (int)__popcll(bal));
}

__global__ __launch_bounds__(256) void wcvt_kernel(const float* __restrict__ w1,
                                                   const float* __restrict__ w2,
                                                   ushort* __restrict__ w1T,
                                                   ushort* __restrict__ w2T)
{
    int idx = blockIdx.x * 256 + threadIdx.x;   // 221184 total
    if (idx < 73728) {                          // 9*128*64
        int ci = idx & 63;
        int co = (idx >> 6) & 127;
        int s  = idx >> 13;
        w1T[idx] = f2bf(w1[(s*64 + ci)*128 + co]);
    } else if (idx < 221184) {
        int i  = idx - 73728;                   // 9*128*128
        int ci = i & 127;
        int co = (i >> 7) & 127;
        int s  = i >> 14;
        w2T[i] = f2bf(w2[(s*128 + ci)*128 + co]);
    }
}

// conv1: 3x3 s2, 64->128. Block = output rows {2g,2g+1} x 128co = 256px.
__global__ __launch_bounds__(512) void conv1_mfma(const float* __restrict__ x,
                                                  const int* __restrict__ mask,
                                                  const ushort* __restrict__ w1T,
                                                  const uchar* __restrict__ m1,
                                                  ushort* __restrict__ out1,
                                                  float* __restrict__ stats)
{
    __shared__ ushort Ah[2 * 258 * 64];   // 66,048 B
    __shared__ ushort Bd[3][8192];        // 3 x 16 KB

    const int t     = threadIdx.x;
    const int lane  = t & 63;
    const int wv    = t >> 6;             // 0..7
    const int wbase = t & ~63;
    const int bid   = blockIdx.x;
    const int L     = (bid & 7) * 32 + (bid >> 3);   // XCD-chunked
    const int g     = L & 63;
    const int b     = L >> 6;

    const int wm = wv >> 1, wn = wv & 1;  // wave: 64px x 64co
    const int lr = lane & 15, lg = lane >> 4;

    auto stageA = [&](int kh) {
        for (int idx = t; idx < 4128; idx += 512) {   // 2 rows x 258c x 8k
            int r   = idx >= 2064;
            int rem = idx - r*2064;
            int c = rem >> 3, k = rem & 7;
            int iw = c - 1;
            int ih = 4*g + 2*r + kh - 1;
            short8 v = {0,0,0,0,0,0,0,0};
            if ((unsigned)ih < 256u && (unsigned)iw < 256u) {
                const int* mr = mask + (size_t)(b*256 + ih) * 256;
                if (mr[iw] == 0) {
                    const float* p = x + ((size_t)(b*256 + ih)*256 + iw)*64 + k*8;
                    float4 fa = *(const float4*)p;
                    float4 fb = *(const float4*)(p + 4);
                    v[0]=(short)f2bf(fa.x); v[1]=(short)f2bf(fa.y);
                    v[2]=(short)f2bf(fa.z); v[3]=(short)f2bf(fa.w);
                    v[4]=(short)f2bf(fb.x); v[5]=(short)f2bf(fb.y);
                    v[6]=(short)f2bf(fb.z); v[7]=(short)f2bf(fb.w);
                }
            }
            int ad = ((r*258 + c)*128 + k*16) ^ ((((unsigned)c >> 1) & 7) << 4);
            *(short8*)((char*)Ah + ad) = v;
        }
    };
    const int coB = t >> 3;               // + r*64
    const int kB  = t & 7;
    auto dmaB = [&](int buf, int tap) {   // 2 VMEM instr/wave
        #pragma unroll
        for (int r = 0; r < 2; ++r) {
            int co = r*64 + coB;
            const ushort* gp = w1T + (size_t)tap*8192 + (size_t)co*64
                             + ((kB ^ (co & 7)) << 3);
            gload_lds16(gp, &Bd[buf][(size_t)(r*512 + wbase)*8]);
        }
    };

    f32x4 acc[4][4];
    #pragma unroll
    for (int mi = 0; mi < 4; ++mi)
        #pragma unroll
        for (int ni = 0; ni < 4; ++ni)
            acc[mi][ni] = (f32x4){0.f, 0.f, 0.f, 0.f};

    stageA(0);
    dmaB(0, 0); dmaB(1, 1); dmaB(2, 2);
    VW4;                                  // B0 landed; B1,B2 in flight
    LK0;                                  // Ah ds_writes done
    SBAR;

    #pragma unroll
    for (int kt = 0; kt < 9; ++kt) {
        const int kw = kt % 3, cb = kt % 3;
        const char* Ab = (const char*)Ah;
        const char* Bb = (const char*)Bd[cb];
        __builtin_amdgcn_s_setprio(1);
        #pragma unroll
        for (int ks = 0; ks < 2; ++ks) {
            short8 af[4], bfr[4];
            #pragma unroll
            for (int mi = 0; mi < 4; ++mi) {
                int px = wm*64 + mi*16 + lr;
                int r  = px >> 7, ow = px & 127;
                int c  = 2*ow + kw;
                af[mi] = *(const short8*)(Ab +
                    (((r*258 + c)*128 + ks*64 + lg*16) ^ ((((unsigned)c >> 1) & 7) << 4)));
            }
            #pragma unroll
            for (int ni = 0; ni < 4; ++ni) {
                int co = wn*64 + ni*16 + lr;
                bfr[ni] = *(const short8*)(Bb +
                    ((co*128 + ks*64 + lg*16) ^ ((co & 7) << 4)));
            }
            #pragma unroll
            for (int mi = 0; mi < 4; ++mi)
                #pragma unroll
                for (int ni = 0; ni < 4; ++ni)
                    acc[mi][ni] = MFMA16(af[mi], bfr[ni], acc[mi][ni], 0, 0, 0);
        }
        __builtin_amdgcn_s_setprio(0);
        if (kt < 8) {
            VW2;                          // B(kt+1) landed; B(kt+2) in flight
            SBAR;
            if (kt <= 5) dmaB(kt % 3, kt + 3);
            if (kw == 2) {                // kh boundary: restage (full drain)
                stageA(kt/3 + 1);
                LK0;
                SBAR;
            }
        }
    }
    __syncthreads();                      // drain; Ah free for epilogue

    const size_t pixbase = (size_t)(b*128 + 2*g) * 128;
    #pragma unroll
    for (int mi = 0; mi < 4; ++mi) {
        #pragma unroll
        for (int ni = 0; ni < 4; ++ni) {
            int p  = wm*64 + mi*16 + lg*4;
            int co = wn*64 + ni*16 + lr;
            #pragma unroll
            for (int r = 0; r < 4; ++r)
                out1[(pixbase + p + r)*128 + co] = f2bf(acc[mi][ni][r]);
        }
    }

    // ---- fused BN1 stats ----
    float s4[4] = {0.f,0.f,0.f,0.f}, q4[4] = {0.f,0.f,0.f,0.f};
    #pragma unroll
    for (int mi = 0; mi < 4; ++mi) {
        const uchar* mp = m1 + pixbase + wm*64 + mi*16 + lg*4;
        #pragma unroll
        for (int r = 0; r < 4; ++r) {
            float a = mp[r] ? 1.f : 0.f;
            #pragma unroll
            for (int ni = 0; ni < 4; ++ni) {
                float av = a * acc[mi][ni][r];
                s4[ni] += av;
                q4[ni] += av * acc[mi][ni][r];
            }
        }
    }
    float* red = (float*)Ah;
    const int rrow = wm*4 + lg;           // 0..15
    #pragma unroll
    for (int ni = 0; ni < 4; ++ni) {
        red[rrow*128 + wn*64 + ni*16 + lr]        = s4[ni];
        red[2048 + rrow*128 + wn*64 + ni*16 + lr] = q4[ni];
    }
    __syncthreads();
    if (t < 128) {
        float v = 0.f, q = 0.f;
        #pragma unroll
        for (int rr = 0; rr < 16; ++rr) { v += red[rr*128 + t]; q += red[2048 + rr*128 + t]; }
        atomicAdd(&stats[t], v);
        atomicAdd(&stats[128 + t], q);
    }
}

// conv2: 3x3 s1, 128->128 on RAW out1 (BN1+ReLU+m1 fused into halo staging).
// Block = output rows {2g,2g+1} x 128co. BK=64: 18 steps, B 3x16KB.
__global__ __launch_bounds__(512) void conv2_mfma(const ushort* __restrict__ a,
                                                  const ushort* __restrict__ w2T,
                                                  const uchar* __restrict__ m1,
                                                  const float* __restrict__ sb,
                                                  float* __restrict__ outraw,
                                                  float* __restrict__ stats)
{
    __shared__ ushort Ah[2 * 130 * 128];  // 66,560 B, swizzle ^((c&7)<<4)
    __shared__ ushort Bd[3][8192];        // 3 x 16 KB
    __shared__ float scb[256];

    const int t     = threadIdx.x;
    const int lane  = t & 63;
    const int wv    = t >> 6;
    const int wbase = t & ~63;
    const int bid   = blockIdx.x;
    const int L     = (bid & 7) * 32 + (bid >> 3);
    const int g     = L & 63;
    const int b     = L >> 6;

    const int wm = wv >> 1, wn = wv & 1;
    const int lr = lane & 15, lg = lane >> 4;

    if (t < 256) scb[t] = sb[t];

    auto stageA = [&](int kh) {
        for (int idx = t; idx < 4160; idx += 512) {   // 2 rows x 130c x 16k
            int r   = idx >= 2080;
            int rem = idx - r*2080;
            int c = rem >> 4, k = rem & 15;
            int iw = c - 1;
            int ih = 2*g + r + kh - 1;
            short8 v = {0,0,0,0,0,0,0,0};
            if ((unsigned)ih < 128u && (unsigned)iw < 128u) {
                const uchar* mr = m1 + (size_t)(b*128 + ih) * 128;
                if (mr[iw]) {
                    short8 rv = *(const short8*)(a + ((size_t)(b*128 + ih)*128 + iw)*128 + k*8);
                    #pragma unroll
                    for (int j = 0; j < 8; ++j) {
                        float f = fmaf(bf2f((ushort)rv[j]), scb[k*8 + j], scb[128 + k*8 + j]);
                        v[j] = (short)f2bf(fmaxf(f, 0.f));
                    }
                }
            }
            int ad = ((r*130 + c)*256 + k*16) ^ ((c & 7) << 4);
            *(short8*)((char*)Ah + ad) = v;
        }
    };
    const int coB = t >> 3;
    const int kB  = t & 7;
    auto dmaB = [&](int buf, int kt) {    // 2 VMEM instr/wave
        const int s = kt / 6, j = kt % 6;
        const int tap = s*3 + (j >> 1);
        const int h = j & 1;
        #pragma unroll
        for (int r = 0; r < 2; ++r) {
            int co = r*64 + coB;
            const ushort* gp = w2T + (size_t)tap*16384 + (size_t)co*128 + h*64
                             + ((kB ^ (co & 7)) << 3);
            gload_lds16(gp, &Bd[buf][(size_t)(r*512 + wbase)*8]);
        }
    };

    f32x4 acc[4][4];
    #pragma unroll
    for (int mi = 0; mi < 4; ++mi)
        #pragma unroll
        for (int ni = 0; ni < 4; ++ni)
            acc[mi][ni] = (f32x4){0.f, 0.f, 0.f, 0.f};

    __syncthreads();                      // scb visible
    stageA(0);
    dmaB(0, 0); dmaB(1, 1); dmaB(2, 2);
    VW4;
    LK0;
    SBAR;

    #pragma unroll
    for (int kt = 0; kt < 18; ++kt) {
        const int j = kt % 6;
        const int kw = j >> 1, h = j & 1, cb = kt % 3;
        const char* Ab = (const char*)Ah;
        const char* Bb = (const char*)Bd[cb];
        __builtin_amdgcn_s_setprio(1);
        #pragma unroll
        for (int ks = 0; ks < 2; ++ks) {
            short8 af[4], bfr[4];
            #pragma unroll
            for (int mi = 0; mi < 4; ++mi) {
                int px = wm*64 + mi*16 + lr;
                int r  = px >> 7, ow = px & 127;
                int c  = ow + kw;
                af[mi] = *(const short8*)(Ab +
                    (((r*130 + c)*256 + h*128 + ks*64 + lg*16) ^ ((c & 7) << 4)));
            }
            #pragma unroll
            for (int ni = 0; ni < 4; ++ni) {
                int co = wn*64 + ni*16 + lr;
                bfr[ni] = *(const short8*)(Bb +
                    ((co*128 + ks*64 + lg*16) ^ ((co & 7) << 4)));
            }
            #pragma unroll
            for (int mi = 0; mi < 4; ++mi)
                #pragma unroll
                for (int ni = 0; ni < 4; ++ni)
                    acc[mi][ni] = MFMA16(af[mi], bfr[ni], acc[mi][ni], 0, 0, 0);
        }
        __builtin_amdgcn_s_setprio(0);
        if (kt < 17) {
            VW2;                          // B(kt+1) landed; B(kt+2) in flight
            SBAR;
            if (kt <= 14) dmaB(kt % 3, kt + 3);
            if (j == 5) {                 // kh boundary: restage (full drain)
                stageA(kt/6 + 1);
                LK0;
                SBAR;
            }
        }
    }
    __syncthreads();

    const size_t pixbase = (size_t)(b*128 + 2*g) * 128;
    #pragma unroll
    for (int mi = 0; mi < 4; ++mi) {
        #pragma unroll
        for (int ni = 0; ni < 4; ++ni) {
            int p  = wm*64 + mi*16 + lg*4;
            int co = wn*64 + ni*16 + lr;
            #pragma unroll
            for (int r = 0; r < 4; ++r)
                outraw[(pixbase + p + r)*128 + co] = acc[mi][ni][r];
        }
    }

    // ---- fused BN2 stats ----
    float s4[4] = {0.f,0.f,0.f,0.f}, q4[4] = {0.f,0.f,0.f,0.f};
    #pragma unroll
    for (int mi = 0; mi < 4; ++mi) {
        const uchar* mp = m1 + pixbase + wm*64 + mi*16 + lg*4;
        #pragma unroll
        for (int r = 0; r < 4; ++r) {
            float a0 = mp[r] ? 1.f : 0.f;
            #pragma unroll
            for (int ni = 0; ni < 4; ++ni) {
                float av = a0 * acc[mi][ni][r];
                s4[ni] += av;
                q4[ni] += av * acc[mi][ni][r];
            }
        }
    }
    float* red = (float*)Ah;
    const int rrow = wm*4 + lg;
    #pragma unroll
    for (int ni = 0; ni < 4; ++ni) {
        red[rrow*128 + wn*64 + ni*16 + lr]        = s4[ni];
        red[2048 + rrow*128 + wn*64 + ni*16 + lr] = q4[ni];
    }
    __syncthreads();
    if (t < 128) {
        float v = 0.f, q = 0.f;
        #pragma unroll
        for (int rr = 0; rr < 16; ++rr) { v += red[rr*128 + t]; q += red[2048 + rr*128 + t]; }
        atomicAdd(&stats[t], v);
        atomicAdd(&stats[128 + t], q);
    }
}

__global__ void finalize_kernel(const float* __restrict__ stats,
                                const float* __restrict__ gamma,
                                const float* __restrict__ beta,
                                float* __restrict__ sbout,
                                const int* __restrict__ cnt)
{
    int c = threadIdx.x;   // 128
    float n = (float)(*cnt);
    float mean = stats[c] / n;
    float var  = stats[128 + c] / n - mean*mean;
    var = fmaxf(var, 0.f);
    float scale = gamma[c] * rsqrtf(var + EPS_BN);
    sbout[c]       = scale;
    sbout[128 + c] = beta[c] - mean*scale;
}

// d_out <- m1 ? raw*sc2+bi2 : 0 (f32 in-place)
__global__ __launch_bounds__(256) void apply_kernel(float* __restrict__ out,
                                                    const uchar* __restrict__ m1,
                                                    const float* __restrict__ sb)
{
    int idx4 = blockIdx.x * 256 + threadIdx.x;   // 2,097,152 float4s
    int pos = idx4 >> 5;
    int c4  = (idx4 & 31) << 2;
    float4 v = ((const float4*)out)[idx4];
    float4 r = make_float4(0.f, 0.f, 0.f, 0.f);
    if (m1[pos]) {
        r.x = fmaf(v.x, sb[c4+0], sb[128+c4+0]);
        r.y = fmaf(v.y, sb[c4+1], sb[128+c4+1]);
        r.z = fmaf(v.z, sb[c4+2], sb[128+c4+2]);
        r.w = fmaf(v.w, sb[c4+3], sb[128+c4+3]);
    }
    ((float4*)out)[idx4] = r;
}

extern "C" void kernel_launch(void* const* d_in, const int* in_sizes, int n_in,
                              void* d_out, int out_size, void* d_ws, size_t ws_size,
                              hipStream_t stream)
{
    const float* x      = (const float*)d_in[0];
    const int*   mask   = (const int*)d_in[1];
    const float* w1     = (const float*)d_in[2];
    const float* gamma1 = (const float*)d_in[3];
    const float* beta1  = (const float*)d_in[4];
    const float* w2     = (const float*)d_in[5];
    const float* gamma2 = (const float*)d_in[6];
    const float* beta2  = (const float*)d_in[7];

    ushort* out1 = (ushort*)d_ws;                    // 65536*128 bf16 (raw conv1)
    ushort* w1T  = out1 + 8388608;                   // 9*128*64
    ushort* w2T  = w1T + 73728;                      // 9*128*128
    float* stats = (float*)(w2T + 147456);           // 512 (256 per BN)
    float* sb    = stats + 512;                      // 512 (256 per BN)
    int*   cnt   = (int*)(sb + 512);                 // 4
    uchar* m1    = (uchar*)(cnt + 4);                // 65536

    float* out = (float*)d_out;

    hipMemsetAsync(stats, 0, 1024*sizeof(float) + 4*sizeof(int), stream);

    mask_kernel <<<256, 256, 0, stream>>>(mask, m1, cnt);
    wcvt_kernel <<<864, 256, 0, stream>>>(w1, w2, w1T, w2T);
    conv1_mfma  <<<256, 512, 0, stream>>>(x, mask, w1T, m1, out1, stats);
    finalize_kernel<<<1, 128, 0, stream>>>(stats, gamma1, beta1, sb, cnt);
    conv2_mfma  <<<256, 512, 0, stream>>>(out1, w2T, m1, sb, out, stats + 256);
    finalize_kernel<<<1, 128, 0, stream>>>(stats + 256, gamma2, beta2, sb + 256, cnt);
    apply_kernel<<<8192, 256, 0, stream>>>(out, m1, sb + 256);
}